// Round 8
// baseline (208.876 us; speedup 1.0000x reference)
//
#include <hip/hip_runtime.h>
#include <hip/hip_bf16.h>
#include <hip/hip_cooperative_groups.h>

namespace cg = cooperative_groups;

// GeneralAttention: fp32 in / fp32 out.
//   q,k,v: [2, 2048, 1024] f32; W_proj: [1024,1024] f32; b_proj: [1024] f32
#define B_SZ 2
#define T_SZ 2048
#define NE   1024
#define NH   16
#define HD   64
#define WIN  64
#define QT   64          // queries per attention tile
#define KT   192         // keys staged per tile = QT + 2*WIN
#define GM   4096        // B*T
#define GN   1024
#define GK   1024
#define KPAD 72          // Ks row stride
#define VPAD 200         // Vt/Ps row stride
#define NBLK 512         // cooperative grid (2/CU; LDS allows 3/CU => co-resident)

__device__ ushort Wb_static[GN * GK];   // 2 MiB bf16 W copy (rewritten every launch)

// ---------- bf16 <-> f32 helpers ----------
__device__ __forceinline__ ushort f2bf(float x) {
    union { float f; uint u; } a; a.f = x;
    uint r = (a.u + 0x7fffu + ((a.u >> 16) & 1u)) >> 16;
    return (ushort)r;
}
__device__ __forceinline__ uint pack2(float a, float b) {
    return (uint)f2bf(a) | ((uint)f2bf(b) << 16);
}
__device__ __forceinline__ uint4 pack8(float4 a, float4 b) {
    return make_uint4(pack2(a.x, a.y), pack2(a.z, a.w),
                      pack2(b.x, b.y), pack2(b.z, b.w));
}

typedef __attribute__((ext_vector_type(8))) short frag_ab;   // 8 bf16
typedef __attribute__((ext_vector_type(4))) float frag_cd;   // 4 fp32

// =====================================================================
// Fused cooperative kernel: [phase 1] windowed MFMA attention (2 tiles
// per block) + W fp32->bf16 convert;  grid.sync();  [phase 2] NT GEMM
// out = y @ Wb^T + bias (128m x 64n tile per block).
// All layouts verified R3-R7. LDS pool 52 KiB shared by both phases.
// =====================================================================
__global__ __launch_bounds__(256) void fused_attn_proj_kernel(
    const float* __restrict__ q, const float* __restrict__ k,
    const float* __restrict__ v, const float* __restrict__ W,
    const float* __restrict__ bias, ushort* __restrict__ y,
    float* __restrict__ C)
{
    __shared__ __attribute__((aligned(16))) ushort pool[KT * KPAD + HD * VPAD]; // 52 KiB
    ushort* Ks = pool;                  // [KT][KPAD]  27.0 KiB (dead after S-phase)
    ushort* Vt = pool + KT * KPAD;      // [HD][VPAD]  25.0 KiB
    ushort* Ps = pool;                  // [QT][VPAD]  25.0 KiB — aliases Ks

    const int t   = threadIdx.x;
    const int blk = blockIdx.x;

    // ---- fused W convert: 1M elems / 512 blocks = 512 float4 / block ----
    {
        const int idx0 = blk * 512 + t;          // float4 index
        const float4 f0 = ((const float4*)W)[idx0];
        const float4 f1 = ((const float4*)W)[idx0 + 256];
        ((uint2*)Wb_static)[idx0]       = make_uint2(pack2(f0.x, f0.y), pack2(f0.z, f0.w));
        ((uint2*)Wb_static)[idx0 + 256] = make_uint2(pack2(f1.x, f1.y), pack2(f1.z, f1.w));
    }

    const int wv   = t >> 6;     // wave 0..3
    const int L    = t & 63;
    const int r16  = L & 15;
    const int quad = L >> 4;

    // ================= PHASE 1: attention, 2 tiles per block =============
    for (int tile = blk; tile < 1024; tile += NBLK) {
        const int qx = tile & 31;
        const int h  = (tile >> 5) & 15;
        const int b  = tile >> 9;
        const int qs = qx * QT;
        const int kstart = qs - WIN;

        __syncthreads();   // protect LDS reuse across iterations

        // ---- stage K (row-major) and V (transposed), fp32 -> bf16 ----
        for (int c = t; c < KT * 8; c += 256) {
            const int j  = c >> 3;
            const int d8 = (c & 7) * 8;
            const int jg = kstart + j;
            float4 k0 = make_float4(0,0,0,0), k1 = make_float4(0,0,0,0);
            float4 v0 = make_float4(0,0,0,0), v1 = make_float4(0,0,0,0);
            if (jg >= 0 && jg < T_SZ) {
                const size_t off = ((size_t)(b * T_SZ + jg)) * NE + h * HD + d8;
                const float4* kp = (const float4*)(k + off);
                const float4* vp = (const float4*)(v + off);
                k0 = kp[0]; k1 = kp[1];
                v0 = vp[0]; v1 = vp[1];
            }
            *(uint4*)&Ks[j * KPAD + d8] = pack8(k0, k1);
            ushort* vtc = &Vt[d8 * VPAD + j];
            vtc[0 * VPAD] = f2bf(v0.x); vtc[1 * VPAD] = f2bf(v0.y);
            vtc[2 * VPAD] = f2bf(v0.z); vtc[3 * VPAD] = f2bf(v0.w);
            vtc[4 * VPAD] = f2bf(v1.x); vtc[5 * VPAD] = f2bf(v1.y);
            vtc[6 * VPAD] = f2bf(v1.z); vtc[7 * VPAD] = f2bf(v1.w);
        }

        // ---- Q A-frags (pre-scaled by 1/8) ----
        frag_ab aq0, aq1;
        {
            const float* qrow = q + ((size_t)(b * T_SZ + qs + wv * 16 + r16)) * NE + h * HD;
            const float4* p0 = (const float4*)(qrow + quad * 8);
            const float4* p1 = (const float4*)(qrow + 32 + quad * 8);
            float4 f0 = p0[0], f1 = p0[1], g0 = p1[0], g1 = p1[1];
            aq0[0] = (short)f2bf(f0.x * 0.125f); aq0[1] = (short)f2bf(f0.y * 0.125f);
            aq0[2] = (short)f2bf(f0.z * 0.125f); aq0[3] = (short)f2bf(f0.w * 0.125f);
            aq0[4] = (short)f2bf(f1.x * 0.125f); aq0[5] = (short)f2bf(f1.y * 0.125f);
            aq0[6] = (short)f2bf(f1.z * 0.125f); aq0[7] = (short)f2bf(f1.w * 0.125f);
            aq1[0] = (short)f2bf(g0.x * 0.125f); aq1[1] = (short)f2bf(g0.y * 0.125f);
            aq1[2] = (short)f2bf(g0.z * 0.125f); aq1[3] = (short)f2bf(g0.w * 0.125f);
            aq1[4] = (short)f2bf(g1.x * 0.125f); aq1[5] = (short)f2bf(g1.y * 0.125f);
            aq1[6] = (short)f2bf(g1.z * 0.125f); aq1[7] = (short)f2bf(g1.w * 0.125f);
        }
        __syncthreads();

        // ---- S = Q K^T ----
        frag_cd sacc[12];
#pragma unroll
        for (int nb = 0; nb < 12; ++nb) sacc[nb] = (frag_cd){0,0,0,0};
#pragma unroll
        for (int nb = 0; nb < 12; ++nb) {
            const frag_ab b0 = *(const frag_ab*)&Ks[(nb * 16 + r16) * KPAD + quad * 8];
            const frag_ab b1 = *(const frag_ab*)&Ks[(nb * 16 + r16) * KPAD + 32 + quad * 8];
            sacc[nb] = __builtin_amdgcn_mfma_f32_16x16x32_bf16(aq0, b0, sacc[nb], 0, 0, 0);
            sacc[nb] = __builtin_amdgcn_mfma_f32_16x16x32_bf16(aq1, b1, sacc[nb], 0, 0, 0);
        }

        // ---- masked fixed-ref softmax in registers ----
        const int base_m = wv * 16 + quad * 4;
        float l[4] = {0.f, 0.f, 0.f, 0.f};
#pragma unroll
        for (int nb = 0; nb < 12; ++nb) {
            const int jl = nb * 16 + r16;
            const int jg = kstart + jl;
            const bool jg_ok = (jg >= 0) & (jg < T_SZ);
#pragma unroll
            for (int r = 0; r < 4; ++r) {
                const int mrow = base_m + r;
                const bool valid = jg_ok & (jl >= mrow) & (jl <= mrow + 2 * WIN);
                const float p = valid ? __expf(sacc[nb][r]) : 0.0f;
                l[r] += p;
                sacc[nb][r] = p;
            }
        }
#pragma unroll
        for (int r = 0; r < 4; ++r) {
            l[r] += __shfl_xor(l[r], 1);
            l[r] += __shfl_xor(l[r], 2);
            l[r] += __shfl_xor(l[r], 4);
            l[r] += __shfl_xor(l[r], 8);
        }

        __syncthreads();   // Ks reads done; safe to overwrite with Ps
#pragma unroll
        for (int nb = 0; nb < 12; ++nb) {
            const int jl = nb * 16 + r16;
#pragma unroll
            for (int r = 0; r < 4; ++r)
                Ps[(base_m + r) * VPAD + jl] = f2bf(sacc[nb][r]);
        }
        __syncthreads();

        // ---- O = P V ----
        frag_ab ap[6];
#pragma unroll
        for (int kb = 0; kb < 6; ++kb)
            ap[kb] = *(const frag_ab*)&Ps[(wv * 16 + r16) * VPAD + kb * 32 + quad * 8];

        frag_cd oacc[4];
#pragma unroll
        for (int nb = 0; nb < 4; ++nb) oacc[nb] = (frag_cd){0,0,0,0};
#pragma unroll
        for (int nb = 0; nb < 4; ++nb) {
#pragma unroll
            for (int kb = 0; kb < 6; ++kb) {
                const frag_ab bv = *(const frag_ab*)&Vt[(nb * 16 + r16) * VPAD + kb * 32 + quad * 8];
                oacc[nb] = __builtin_amdgcn_mfma_f32_16x16x32_bf16(ap[kb], bv, oacc[nb], 0, 0, 0);
            }
        }

        // ---- normalize + store y (bf16) ----
        float inv[4];
#pragma unroll
        for (int r = 0; r < 4; ++r) inv[r] = 1.0f / l[r];
#pragma unroll
        for (int nb = 0; nb < 4; ++nb) {
#pragma unroll
            for (int r = 0; r < 4; ++r) {
                const int iq = qs + base_m + r;
                const int d  = nb * 16 + r16;
                y[((size_t)(b * T_SZ + iq)) * NE + h * HD + d] = f2bf(oacc[nb][r] * inv[r]);
            }
        }
    }

    // ================= grid-wide barrier (device-scope fence) ============
    cg::this_grid().sync();

    // ================= PHASE 2: projection GEMM, 1 tile per block ========
    // 128m x 64n tile, BK=32, global_load_lds w16.
    {
        ushort* As = pool;              // [128][32] 8 KiB
        ushort* Bs = pool + 128 * 32;   // [64][32]  4 KiB

        const int tile_n = blk & 15;    // 0..15
        const int tile_m = blk >> 4;    // 0..31
        const int wm     = wv >> 1;
        const int wn     = wv & 1;

        const int r0  = t >> 2;
        const int sk8 = (t & 3) * 8;
        const ushort* gA0 = y + (size_t)(tile_m * 128 + r0)      * GK + sk8;
        const ushort* gA1 = y + (size_t)(tile_m * 128 + r0 + 64) * GK + sk8;
        const ushort* gB  = Wb_static + (size_t)(tile_n * 64 + r0) * GK + sk8;

        frag_cd acc[4][2];
#pragma unroll
        for (int mi = 0; mi < 4; ++mi)
#pragma unroll
            for (int ni = 0; ni < 2; ++ni)
                acc[mi][ni] = (frag_cd){0.0f, 0.0f, 0.0f, 0.0f};

        const int fm = wm * 64 + r16;
        const int fn = wn * 32 + r16;
        const int fk = quad * 8;

        __syncthreads();   // phase-1 LDS reads all done before restage

        for (int k0 = 0; k0 < GK; k0 += 32) {
            __builtin_amdgcn_global_load_lds(
                (const __attribute__((address_space(1))) unsigned int*)(gA0 + k0),
                (__attribute__((address_space(3))) unsigned int*)(As + t * 8), 16, 0, 0);
            __builtin_amdgcn_global_load_lds(
                (const __attribute__((address_space(1))) unsigned int*)(gA1 + k0),
                (__attribute__((address_space(3))) unsigned int*)(As + (t + 256) * 8), 16, 0, 0);
            __builtin_amdgcn_global_load_lds(
                (const __attribute__((address_space(1))) unsigned int*)(gB + k0),
                (__attribute__((address_space(3))) unsigned int*)(Bs + t * 8), 16, 0, 0);
            __syncthreads();

            frag_ab af[4], bf[2];
#pragma unroll
            for (int mi = 0; mi < 4; ++mi)
                af[mi] = *(const frag_ab*)&As[(fm + mi * 16) * 32 + fk];
#pragma unroll
            for (int ni = 0; ni < 2; ++ni)
                bf[ni] = *(const frag_ab*)&Bs[(fn + ni * 16) * 32 + fk];

#pragma unroll
            for (int mi = 0; mi < 4; ++mi)
#pragma unroll
                for (int ni = 0; ni < 2; ++ni)
                    acc[mi][ni] = __builtin_amdgcn_mfma_f32_16x16x32_bf16(
                        af[mi], bf[ni], acc[mi][ni], 0, 0, 0);

            __syncthreads();
        }

#pragma unroll
        for (int mi = 0; mi < 4; ++mi) {
#pragma unroll
            for (int ni = 0; ni < 2; ++ni) {
                const int rbase = tile_m * 128 + wm * 64 + mi * 16 + quad * 4;
                const int cg_   = tile_n * 64 + wn * 32 + ni * 16 + r16;
                const float bv  = bias[cg_];
#pragma unroll
                for (int r = 0; r < 4; ++r)
                    C[(size_t)(rbase + r) * GN + cg_] = acc[mi][ni][r] + bv;
            }
        }
    }
}

extern "C" void kernel_launch(void* const* d_in, const int* in_sizes, int n_in,
                              void* d_out, int out_size, void* d_ws, size_t ws_size,
                              hipStream_t stream) {
    (void)in_sizes; (void)n_in; (void)out_size; (void)ws_size;
    const float* q    = (const float*)d_in[0];
    const float* k    = (const float*)d_in[1];
    const float* v    = (const float*)d_in[2];
    const float* W    = (const float*)d_in[3];
    const float* bias = (const float*)d_in[4];
    float*  out = (float*)d_out;
    ushort* y   = (ushort*)d_ws;   // 8 MiB bf16 scratch (ws is 256 MiB)

    void* args[] = {(void*)&q, (void*)&k, (void*)&v, (void*)&W,
                    (void*)&bias, (void*)&y, (void*)&out};
    hipLaunchCooperativeKernel((const void*)fused_attn_proj_kernel,
                               dim3(NBLK), dim3(256), args, 0, stream);
}

// Round 9
// 160.982 us; speedup vs baseline: 1.2975x; 1.2975x over previous
//
#include <hip/hip_runtime.h>
#include <hip/hip_bf16.h>

// GeneralAttention: fp32 in / fp32 out.
//   q,k,v: [2, 2048, 1024] f32; W_proj: [1024,1024] f32; b_proj: [1024] f32
#define B_SZ 2
#define T_SZ 2048
#define NE   1024
#define NH   16
#define HD   64
#define WIN  64
#define QT   64          // queries per attention tile
#define KT   192         // keys staged per tile = QT + 2*WIN
#define GM   4096        // B*T
#define GN   1024
#define GK   1024
#define KPAD 72          // Ks row stride
#define VPAD 200         // Vt/Ps row stride

__device__ ushort Wb_static[GN * GK];   // 2 MiB bf16 W copy (rewritten every launch)

// ---------- bf16 <-> f32 helpers ----------
__device__ __forceinline__ ushort f2bf(float x) {
    union { float f; uint u; } a; a.f = x;
    uint r = (a.u + 0x7fffu + ((a.u >> 16) & 1u)) >> 16;
    return (ushort)r;
}
__device__ __forceinline__ uint pack2(float a, float b) {
    return (uint)f2bf(a) | ((uint)f2bf(b) << 16);
}
__device__ __forceinline__ uint4 pack8(float4 a, float4 b) {
    return make_uint4(pack2(a.x, a.y), pack2(a.z, a.w),
                      pack2(b.x, b.y), pack2(b.z, b.w));
}

typedef __attribute__((ext_vector_type(8))) short frag_ab;   // 8 bf16
typedef __attribute__((ext_vector_type(4))) float frag_cd;   // 4 fp32

// =====================================================================
// Kernel 1: MFMA windowed attention + fused W fp32->bf16 convert.
// grid (T/QT, NH, B) = 1024 blocks, block 256 = 4 waves.
// Vt uses an 8-group XOR swizzle: element (d, j) lives at
//   Vt[d*VPAD + ((j>>3) ^ ((d>>3)&7))*8 + (j&7)]
// -> transpose-staging stores hit 8 distinct banks (was 8-way same-bank),
//    frag reads remain contiguous 16B-aligned.
// =====================================================================
__global__ __launch_bounds__(256) void attn_mfma_kernel(
    const float* __restrict__ q, const float* __restrict__ k,
    const float* __restrict__ v, const float* __restrict__ W,
    ushort* __restrict__ y)
{
    __shared__ __attribute__((aligned(16))) ushort pool[KT * KPAD + HD * VPAD]; // 52 KiB
    ushort* Ks = pool;                  // [KT][KPAD]  27.0 KiB (dead after S-phase)
    ushort* Vt = pool + KT * KPAD;      // [HD][VPAD]  25.0 KiB (swizzled)
    ushort* Ps = pool;                  // [QT][VPAD]  25.0 KiB — aliases Ks

    const int qs = blockIdx.x * QT;
    const int h  = blockIdx.y;
    const int b  = blockIdx.z;
    const int t  = threadIdx.x;
    const int kstart = qs - WIN;

    // ---- fused W convert: this block converts 1024 elems (4/thread) ----
    {
        const int bid = blockIdx.x + 32 * blockIdx.y + 512 * blockIdx.z; // 0..1023
        const int idx = bid * 256 + t;                                   // float4 index
        const float4 f = ((const float4*)W)[idx];
        ((uint2*)Wb_static)[idx] = make_uint2(pack2(f.x, f.y), pack2(f.z, f.w));
    }

    // ---- stage K (row-major) and V (transposed+swizzled), fp32 -> bf16 ----
    for (int c = t; c < KT * 8; c += 256) {
        const int j  = c >> 3;          // key 0..191
        const int cc = c & 7;           // dim-chunk = d>>3 for the 8 stores
        const int d8 = cc * 8;
        const int jg = kstart + j;
        float4 k0 = make_float4(0,0,0,0), k1 = make_float4(0,0,0,0);
        float4 v0 = make_float4(0,0,0,0), v1 = make_float4(0,0,0,0);
        if (jg >= 0 && jg < T_SZ) {
            const size_t off = ((size_t)(b * T_SZ + jg)) * NE + h * HD + d8;
            const float4* kp = (const float4*)(k + off);
            const float4* vp = (const float4*)(v + off);
            k0 = kp[0]; k1 = kp[1];
            v0 = vp[0]; v1 = vp[1];
        }
        *(uint4*)&Ks[j * KPAD + d8] = pack8(k0, k1);
        // swizzled transpose store: col = ((j>>3) ^ cc)*8 + (j&7)
        ushort* vtc = &Vt[d8 * VPAD + (((j >> 3) ^ cc) * 8 + (j & 7))];
        vtc[0 * VPAD] = f2bf(v0.x); vtc[1 * VPAD] = f2bf(v0.y);
        vtc[2 * VPAD] = f2bf(v0.z); vtc[3 * VPAD] = f2bf(v0.w);
        vtc[4 * VPAD] = f2bf(v1.x); vtc[5 * VPAD] = f2bf(v1.y);
        vtc[6 * VPAD] = f2bf(v1.z); vtc[7 * VPAD] = f2bf(v1.w);
    }

    const int wv   = t >> 6;     // wave 0..3
    const int L    = t & 63;
    const int r16  = L & 15;
    const int quad = L >> 4;

    // ---- Q A-frags (pre-scaled by 1/8) ----
    frag_ab aq0, aq1;
    {
        const float* qrow = q + ((size_t)(b * T_SZ + qs + wv * 16 + r16)) * NE + h * HD;
        const float4* p0 = (const float4*)(qrow + quad * 8);
        const float4* p1 = (const float4*)(qrow + 32 + quad * 8);
        float4 f0 = p0[0], f1 = p0[1], g0 = p1[0], g1 = p1[1];
        aq0[0] = (short)f2bf(f0.x * 0.125f); aq0[1] = (short)f2bf(f0.y * 0.125f);
        aq0[2] = (short)f2bf(f0.z * 0.125f); aq0[3] = (short)f2bf(f0.w * 0.125f);
        aq0[4] = (short)f2bf(f1.x * 0.125f); aq0[5] = (short)f2bf(f1.y * 0.125f);
        aq0[6] = (short)f2bf(f1.z * 0.125f); aq0[7] = (short)f2bf(f1.w * 0.125f);
        aq1[0] = (short)f2bf(g0.x * 0.125f); aq1[1] = (short)f2bf(g0.y * 0.125f);
        aq1[2] = (short)f2bf(g0.z * 0.125f); aq1[3] = (short)f2bf(g0.w * 0.125f);
        aq1[4] = (short)f2bf(g1.x * 0.125f); aq1[5] = (short)f2bf(g1.y * 0.125f);
        aq1[6] = (short)f2bf(g1.z * 0.125f); aq1[7] = (short)f2bf(g1.w * 0.125f);
    }
    __syncthreads();

    // ---- S = Q K^T : 12 key-blocks x (K=64 -> 2 mfma) ----
    frag_cd sacc[12];
#pragma unroll
    for (int nb = 0; nb < 12; ++nb) sacc[nb] = (frag_cd){0,0,0,0};
#pragma unroll
    for (int nb = 0; nb < 12; ++nb) {
        const frag_ab b0 = *(const frag_ab*)&Ks[(nb * 16 + r16) * KPAD + quad * 8];
        const frag_ab b1 = *(const frag_ab*)&Ks[(nb * 16 + r16) * KPAD + 32 + quad * 8];
        sacc[nb] = __builtin_amdgcn_mfma_f32_16x16x32_bf16(aq0, b0, sacc[nb], 0, 0, 0);
        sacc[nb] = __builtin_amdgcn_mfma_f32_16x16x32_bf16(aq1, b1, sacc[nb], 0, 0, 0);
    }

    // ---- masked fixed-ref softmax in registers ----
    const int base_m = wv * 16 + quad * 4;
    float l[4] = {0.f, 0.f, 0.f, 0.f};
#pragma unroll
    for (int nb = 0; nb < 12; ++nb) {
        const int jl = nb * 16 + r16;
        const int jg = kstart + jl;
        const bool jg_ok = (jg >= 0) & (jg < T_SZ);
#pragma unroll
        for (int r = 0; r < 4; ++r) {
            const int mrow = base_m + r;
            const bool valid = jg_ok & (jl >= mrow) & (jl <= mrow + 2 * WIN);
            const float p = valid ? __expf(sacc[nb][r]) : 0.0f;
            l[r] += p;
            sacc[nb][r] = p;
        }
    }
#pragma unroll
    for (int r = 0; r < 4; ++r) {
        l[r] += __shfl_xor(l[r], 1);
        l[r] += __shfl_xor(l[r], 2);
        l[r] += __shfl_xor(l[r], 4);
        l[r] += __shfl_xor(l[r], 8);
    }

    __syncthreads();   // Ks reads done; safe to overwrite with Ps
#pragma unroll
    for (int nb = 0; nb < 12; ++nb) {
        const int jl = nb * 16 + r16;
#pragma unroll
        for (int r = 0; r < 4; ++r)
            Ps[(base_m + r) * VPAD + jl] = f2bf(sacc[nb][r]);
    }
    __syncthreads();

    // ---- O = P V : P A-frags, swizzled V^T B-frags ----
    frag_ab ap[6];
#pragma unroll
    for (int kb = 0; kb < 6; ++kb)
        ap[kb] = *(const frag_ab*)&Ps[(wv * 16 + r16) * VPAD + kb * 32 + quad * 8];

    frag_cd oacc[4];
#pragma unroll
    for (int nb = 0; nb < 4; ++nb) oacc[nb] = (frag_cd){0,0,0,0};
#pragma unroll
    for (int nb = 0; nb < 4; ++nb) {
        const int dr  = nb * 16 + r16;
        const int dsw = (dr >> 3) & 7;
#pragma unroll
        for (int kb = 0; kb < 6; ++kb) {
            const frag_ab bv = *(const frag_ab*)&Vt[dr * VPAD + (((kb * 4 + quad) ^ dsw) * 8)];
            oacc[nb] = __builtin_amdgcn_mfma_f32_16x16x32_bf16(ap[kb], bv, oacc[nb], 0, 0, 0);
        }
    }

    // ---- normalize + store y (bf16) ----
    float inv[4];
#pragma unroll
    for (int r = 0; r < 4; ++r) inv[r] = 1.0f / l[r];
#pragma unroll
    for (int nb = 0; nb < 4; ++nb) {
#pragma unroll
        for (int r = 0; r < 4; ++r) {
            const int iq = qs + base_m + r;
            const int d  = nb * 16 + r16;
            y[((size_t)(b * T_SZ + iq)) * NE + h * HD + d] = f2bf(oacc[nb][r] * inv[r]);
        }
    }
}

// =====================================================================
// Kernel 2: barrier-free direct-global NT GEMM. out = y @ Wb^T + bias.
// grid (16, 32) = 512 blocks, 4 waves each; wave tile 64m x 32n (4x2
// frags). NO LDS, NO barriers: A/B frags load straight from global bf16
// (per frag: 16 rows x 64B contiguous -> clean dwordx4 pattern, L2-served;
// total L2 traffic ~192 MB ~= 5.6 us at L2 BW). Compiler software-
// pipelines loads vs MFMA with fine-grained vmcnt — no barrier drain.
// =====================================================================
__global__ __launch_bounds__(256) void proj_gemm_direct_kernel(
    const ushort* __restrict__ A,
    const float* __restrict__ bias, float* __restrict__ C)
{
    const ushort* Bw = Wb_static;
    const int t      = threadIdx.x;
    const int tile_n = blockIdx.x;   // 0..15
    const int tile_m = blockIdx.y;   // 0..31
    const int lane   = t & 63;
    const int wv     = t >> 6;
    const int wm     = wv >> 1;      // 0..1
    const int wn     = wv & 1;       // 0..1
    const int r16    = lane & 15;
    const int quad   = lane >> 4;

    const ushort* pa[4];
    const ushort* pb[2];
#pragma unroll
    for (int mi = 0; mi < 4; ++mi)
        pa[mi] = A + (size_t)(tile_m * 128 + wm * 64 + mi * 16 + r16) * GK + quad * 8;
#pragma unroll
    for (int ni = 0; ni < 2; ++ni)
        pb[ni] = Bw + (size_t)(tile_n * 64 + wn * 32 + ni * 16 + r16) * GK + quad * 8;

    frag_cd acc[4][2];
#pragma unroll
    for (int mi = 0; mi < 4; ++mi)
#pragma unroll
        for (int ni = 0; ni < 2; ++ni)
            acc[mi][ni] = (frag_cd){0.0f, 0.0f, 0.0f, 0.0f};

    for (int k0 = 0; k0 < GK; k0 += 64) {     // 16 iters, 2 k-steps each
        frag_ab a0[4], a1[4], b0[2], b1[2];
#pragma unroll
        for (int mi = 0; mi < 4; ++mi) {
            a0[mi] = *(const frag_ab*)(pa[mi] + k0);
            a1[mi] = *(const frag_ab*)(pa[mi] + k0 + 32);
        }
#pragma unroll
        for (int ni = 0; ni < 2; ++ni) {
            b0[ni] = *(const frag_ab*)(pb[ni] + k0);
            b1[ni] = *(const frag_ab*)(pb[ni] + k0 + 32);
        }
#pragma unroll
        for (int mi = 0; mi < 4; ++mi)
#pragma unroll
            for (int ni = 0; ni < 2; ++ni) {
                acc[mi][ni] = __builtin_amdgcn_mfma_f32_16x16x32_bf16(
                    a0[mi], b0[ni], acc[mi][ni], 0, 0, 0);
                acc[mi][ni] = __builtin_amdgcn_mfma_f32_16x16x32_bf16(
                    a1[mi], b1[ni], acc[mi][ni], 0, 0, 0);
            }
    }

#pragma unroll
    for (int mi = 0; mi < 4; ++mi) {
#pragma unroll
        for (int ni = 0; ni < 2; ++ni) {
            const int rbase = tile_m * 128 + wm * 64 + mi * 16 + quad * 4;
            const int cg    = tile_n * 64 + wn * 32 + ni * 16 + r16;
            const float bv  = bias[cg];
#pragma unroll
            for (int r = 0; r < 4; ++r)
                C[(size_t)(rbase + r) * GN + cg] = acc[mi][ni][r] + bv;
        }
    }
}

extern "C" void kernel_launch(void* const* d_in, const int* in_sizes, int n_in,
                              void* d_out, int out_size, void* d_ws, size_t ws_size,
                              hipStream_t stream) {
    (void)in_sizes; (void)n_in; (void)out_size; (void)ws_size;
    const float* q    = (const float*)d_in[0];
    const float* k    = (const float*)d_in[1];
    const float* v    = (const float*)d_in[2];
    const float* W    = (const float*)d_in[3];
    const float* bias = (const float*)d_in[4];
    float*  out = (float*)d_out;
    ushort* y   = (ushort*)d_ws;   // 8 MiB bf16 scratch

    dim3 g1(T_SZ / QT, NH, B_SZ);          // (32, 16, 2) = 1024 blocks
    attn_mfma_kernel<<<g1, 256, 0, stream>>>(q, k, v, W, y);

    dim3 g2(GN / 64, GM / 128);            // (16, 32) = 512 blocks
    proj_gemm_direct_kernel<<<g2, 256, 0, stream>>>(y, bias, out);
}

// Round 10
// 128.976 us; speedup vs baseline: 1.6195x; 1.2482x over previous
//
#include <hip/hip_runtime.h>
#include <hip/hip_bf16.h>

// GeneralAttention: fp32 in / fp32 out.
//   q,k,v: [2, 2048, 1024] f32; W_proj: [1024,1024] f32; b_proj: [1024] f32
#define B_SZ 2
#define T_SZ 2048
#define NE   1024
#define NH   16
#define HD   64
#define WIN  64
#define QT   64          // queries per attention tile
#define KT   192         // keys staged per tile = QT + 2*WIN
#define GM   4096        // B*T
#define GN   1024
#define GK   1024
#define KPAD 72          // Ks row stride (36 dw == 4 mod 32 -> spread banks)
#define VPAD 200         // Vt/Ps row stride (100 dw == 4 mod 32)

__device__ ushort Wb_static[GN * GK];   // 2 MiB bf16 W copy (rewritten every launch)

// ---------- bf16 <-> f32 helpers ----------
__device__ __forceinline__ ushort f2bf(float x) {
    union { float f; uint u; } a; a.f = x;
    uint r = (a.u + 0x7fffu + ((a.u >> 16) & 1u)) >> 16;
    return (ushort)r;
}
__device__ __forceinline__ uint pack2(float a, float b) {
    return (uint)f2bf(a) | ((uint)f2bf(b) << 16);
}
__device__ __forceinline__ uint4 pack8(float4 a, float4 b) {
    return make_uint4(pack2(a.x, a.y), pack2(a.z, a.w),
                      pack2(b.x, b.y), pack2(b.z, b.w));
}

typedef __attribute__((ext_vector_type(8))) short frag_ab;   // 8 bf16
typedef __attribute__((ext_vector_type(4))) float frag_cd;   // 4 fp32

// =====================================================================
// Kernel 1: MFMA windowed attention + fused W fp32->bf16 convert.
// (identical to R9 — Vt XOR store swizzle, Ps aliases Ks, 52 KiB LDS)
// =====================================================================
__global__ __launch_bounds__(256) void attn_mfma_kernel(
    const float* __restrict__ q, const float* __restrict__ k,
    const float* __restrict__ v, const float* __restrict__ W,
    ushort* __restrict__ y)
{
    __shared__ __attribute__((aligned(16))) ushort pool[KT * KPAD + HD * VPAD]; // 52 KiB
    ushort* Ks = pool;                  // [KT][KPAD]  27.0 KiB (dead after S-phase)
    ushort* Vt = pool + KT * KPAD;      // [HD][VPAD]  25.0 KiB (swizzled)
    ushort* Ps = pool;                  // [QT][VPAD]  25.0 KiB — aliases Ks

    const int qs = blockIdx.x * QT;
    const int h  = blockIdx.y;
    const int b  = blockIdx.z;
    const int t  = threadIdx.x;
    const int kstart = qs - WIN;

    // ---- fused W convert: this block converts 1024 elems (4/thread) ----
    {
        const int bid = blockIdx.x + 32 * blockIdx.y + 512 * blockIdx.z; // 0..1023
        const int idx = bid * 256 + t;                                   // float4 index
        const float4 f = ((const float4*)W)[idx];
        ((uint2*)Wb_static)[idx] = make_uint2(pack2(f.x, f.y), pack2(f.z, f.w));
    }

    // ---- stage K (row-major) and V (transposed+swizzled), fp32 -> bf16 ----
    for (int c = t; c < KT * 8; c += 256) {
        const int j  = c >> 3;          // key 0..191
        const int cc = c & 7;           // dim-chunk
        const int d8 = cc * 8;
        const int jg = kstart + j;
        float4 k0 = make_float4(0,0,0,0), k1 = make_float4(0,0,0,0);
        float4 v0 = make_float4(0,0,0,0), v1 = make_float4(0,0,0,0);
        if (jg >= 0 && jg < T_SZ) {
            const size_t off = ((size_t)(b * T_SZ + jg)) * NE + h * HD + d8;
            const float4* kp = (const float4*)(k + off);
            const float4* vp = (const float4*)(v + off);
            k0 = kp[0]; k1 = kp[1];
            v0 = vp[0]; v1 = vp[1];
        }
        *(uint4*)&Ks[j * KPAD + d8] = pack8(k0, k1);
        // swizzled transpose store: col = ((j>>3) ^ cc)*8 + (j&7)
        ushort* vtc = &Vt[d8 * VPAD + (((j >> 3) ^ cc) * 8 + (j & 7))];
        vtc[0 * VPAD] = f2bf(v0.x); vtc[1 * VPAD] = f2bf(v0.y);
        vtc[2 * VPAD] = f2bf(v0.z); vtc[3 * VPAD] = f2bf(v0.w);
        vtc[4 * VPAD] = f2bf(v1.x); vtc[5 * VPAD] = f2bf(v1.y);
        vtc[6 * VPAD] = f2bf(v1.z); vtc[7 * VPAD] = f2bf(v1.w);
    }

    const int wv   = t >> 6;     // wave 0..3
    const int L    = t & 63;
    const int r16  = L & 15;
    const int quad = L >> 4;

    // ---- Q A-frags (pre-scaled by 1/8) ----
    frag_ab aq0, aq1;
    {
        const float* qrow = q + ((size_t)(b * T_SZ + qs + wv * 16 + r16)) * NE + h * HD;
        const float4* p0 = (const float4*)(qrow + quad * 8);
        const float4* p1 = (const float4*)(qrow + 32 + quad * 8);
        float4 f0 = p0[0], f1 = p0[1], g0 = p1[0], g1 = p1[1];
        aq0[0] = (short)f2bf(f0.x * 0.125f); aq0[1] = (short)f2bf(f0.y * 0.125f);
        aq0[2] = (short)f2bf(f0.z * 0.125f); aq0[3] = (short)f2bf(f0.w * 0.125f);
        aq0[4] = (short)f2bf(f1.x * 0.125f); aq0[5] = (short)f2bf(f1.y * 0.125f);
        aq0[6] = (short)f2bf(f1.z * 0.125f); aq0[7] = (short)f2bf(f1.w * 0.125f);
        aq1[0] = (short)f2bf(g0.x * 0.125f); aq1[1] = (short)f2bf(g0.y * 0.125f);
        aq1[2] = (short)f2bf(g0.z * 0.125f); aq1[3] = (short)f2bf(g0.w * 0.125f);
        aq1[4] = (short)f2bf(g1.x * 0.125f); aq1[5] = (short)f2bf(g1.y * 0.125f);
        aq1[6] = (short)f2bf(g1.z * 0.125f); aq1[7] = (short)f2bf(g1.w * 0.125f);
    }
    __syncthreads();

    // ---- S = Q K^T ----
    frag_cd sacc[12];
#pragma unroll
    for (int nb = 0; nb < 12; ++nb) sacc[nb] = (frag_cd){0,0,0,0};
#pragma unroll
    for (int nb = 0; nb < 12; ++nb) {
        const frag_ab b0 = *(const frag_ab*)&Ks[(nb * 16 + r16) * KPAD + quad * 8];
        const frag_ab b1 = *(const frag_ab*)&Ks[(nb * 16 + r16) * KPAD + 32 + quad * 8];
        sacc[nb] = __builtin_amdgcn_mfma_f32_16x16x32_bf16(aq0, b0, sacc[nb], 0, 0, 0);
        sacc[nb] = __builtin_amdgcn_mfma_f32_16x16x32_bf16(aq1, b1, sacc[nb], 0, 0, 0);
    }

    // ---- masked fixed-ref softmax in registers ----
    const int base_m = wv * 16 + quad * 4;
    float l[4] = {0.f, 0.f, 0.f, 0.f};
#pragma unroll
    for (int nb = 0; nb < 12; ++nb) {
        const int jl = nb * 16 + r16;
        const int jg = kstart + jl;
        const bool jg_ok = (jg >= 0) & (jg < T_SZ);
#pragma unroll
        for (int r = 0; r < 4; ++r) {
            const int mrow = base_m + r;
            const bool valid = jg_ok & (jl >= mrow) & (jl <= mrow + 2 * WIN);
            const float p = valid ? __expf(sacc[nb][r]) : 0.0f;
            l[r] += p;
            sacc[nb][r] = p;
        }
    }
#pragma unroll
    for (int r = 0; r < 4; ++r) {
        l[r] += __shfl_xor(l[r], 1);
        l[r] += __shfl_xor(l[r], 2);
        l[r] += __shfl_xor(l[r], 4);
        l[r] += __shfl_xor(l[r], 8);
    }

    __syncthreads();   // Ks reads done; safe to overwrite with Ps
#pragma unroll
    for (int nb = 0; nb < 12; ++nb) {
        const int jl = nb * 16 + r16;
#pragma unroll
        for (int r = 0; r < 4; ++r)
            Ps[(base_m + r) * VPAD + jl] = f2bf(sacc[nb][r]);
    }
    __syncthreads();

    // ---- O = P V ----
    frag_ab ap[6];
#pragma unroll
    for (int kb = 0; kb < 6; ++kb)
        ap[kb] = *(const frag_ab*)&Ps[(wv * 16 + r16) * VPAD + kb * 32 + quad * 8];

    frag_cd oacc[4];
#pragma unroll
    for (int nb = 0; nb < 4; ++nb) oacc[nb] = (frag_cd){0,0,0,0};
#pragma unroll
    for (int nb = 0; nb < 4; ++nb) {
        const int dr  = nb * 16 + r16;
        const int dsw = (dr >> 3) & 7;
#pragma unroll
        for (int kb = 0; kb < 6; ++kb) {
            const frag_ab bv = *(const frag_ab*)&Vt[dr * VPAD + (((kb * 4 + quad) ^ dsw) * 8)];
            oacc[nb] = __builtin_amdgcn_mfma_f32_16x16x32_bf16(ap[kb], bv, oacc[nb], 0, 0, 0);
        }
    }

    // ---- normalize + store y (bf16) ----
    float inv[4];
#pragma unroll
    for (int r = 0; r < 4; ++r) inv[r] = 1.0f / l[r];
#pragma unroll
    for (int nb = 0; nb < 4; ++nb) {
#pragma unroll
        for (int r = 0; r < 4; ++r) {
            const int iq = qs + base_m + r;
            const int d  = nb * 16 + r16;
            y[((size_t)(b * T_SZ + iq)) * NE + h * HD + d] = f2bf(oacc[nb][r] * inv[r]);
        }
    }
}

// =====================================================================
// Kernel 2: LDS-staged NT GEMM, 128m x 64n tile, BK=64, XOR bank swizzle.
// grid (16, 32) = 512 blocks (2/CU), 4 waves as 2m x 2n (wave 64x32).
// LDS 24 KiB. global_load_lds w16. LDS[row][c] = global[row][c ^ (row&7)]
// (chunk = 8 ushorts): frag b128 reads then hit all 32 banks balanced
// (was 16 banks @ stride-32 rows -> the 1.05M conflicts in R6/R7).
// =====================================================================
__global__ __launch_bounds__(256) void proj_gemm_kernel(
    const ushort* __restrict__ A,
    const float* __restrict__ bias, float* __restrict__ C)
{
    __shared__ __attribute__((aligned(16))) ushort As[128 * 64];  // 16 KiB
    __shared__ __attribute__((aligned(16))) ushort Bs[64 * 64];   //  8 KiB

    const ushort* Bw = Wb_static;
    const int t      = threadIdx.x;
    const int tile_n = blockIdx.x;   // 0..15
    const int tile_m = blockIdx.y;   // 0..31
    const int lane   = t & 63;
    const int wv     = t >> 6;
    const int wm     = wv >> 1;      // 0..1
    const int wn     = wv & 1;       // 0..1
    const int r16    = lane & 15;
    const int quad   = lane >> 4;

    frag_cd acc[4][2];
#pragma unroll
    for (int mi = 0; mi < 4; ++mi)
#pragma unroll
        for (int ni = 0; ni < 2; ++ni)
            acc[mi][ni] = (frag_cd){0.0f, 0.0f, 0.0f, 0.0f};

    const int fm  = wm * 64 + r16;            // A row base (add mi*16)
    const int fn  = wn * 32 + r16;            // B row base (add ni*16)
    const int sw  = r16 & 7;                  // XOR key (row&7 of all frag rows)
    const int ca0 = (quad ^ sw) * 8;          // LDS col for global chunk quad
    const int ca1 = ((4 + quad) ^ sw) * 8;    // LDS col for global chunk 4+quad

    for (int k0 = 0; k0 < GK; k0 += 64) {
        // stage A: 1024 chunks (4/thread); B: 512 chunks (2/thread)
#pragma unroll
        for (int i = 0; i < 4; ++i) {
            const int c   = t + 256 * i;
            const int row = c >> 3;
            const int src = ((c & 7) ^ (row & 7)) * 8;
            __builtin_amdgcn_global_load_lds(
                (const __attribute__((address_space(1))) unsigned int*)
                    (A + (size_t)(tile_m * 128 + row) * GK + k0 + src),
                (__attribute__((address_space(3))) unsigned int*)(As + c * 8), 16, 0, 0);
        }
#pragma unroll
        for (int i = 0; i < 2; ++i) {
            const int c   = t + 256 * i;
            const int row = c >> 3;
            const int src = ((c & 7) ^ (row & 7)) * 8;
            __builtin_amdgcn_global_load_lds(
                (const __attribute__((address_space(1))) unsigned int*)
                    (Bw + (size_t)(tile_n * 64 + row) * GK + k0 + src),
                (__attribute__((address_space(3))) unsigned int*)(Bs + c * 8), 16, 0, 0);
        }
        __syncthreads();

        frag_ab a0[4], a1[4], b0[2], b1[2];
#pragma unroll
        for (int mi = 0; mi < 4; ++mi) {
            a0[mi] = *(const frag_ab*)&As[(fm + mi * 16) * 64 + ca0];
            a1[mi] = *(const frag_ab*)&As[(fm + mi * 16) * 64 + ca1];
        }
#pragma unroll
        for (int ni = 0; ni < 2; ++ni) {
            b0[ni] = *(const frag_ab*)&Bs[(fn + ni * 16) * 64 + ca0];
            b1[ni] = *(const frag_ab*)&Bs[(fn + ni * 16) * 64 + ca1];
        }

#pragma unroll
        for (int mi = 0; mi < 4; ++mi)
#pragma unroll
            for (int ni = 0; ni < 2; ++ni) {
                acc[mi][ni] = __builtin_amdgcn_mfma_f32_16x16x32_bf16(
                    a0[mi], b0[ni], acc[mi][ni], 0, 0, 0);
                acc[mi][ni] = __builtin_amdgcn_mfma_f32_16x16x32_bf16(
                    a1[mi], b1[ni], acc[mi][ni], 0, 0, 0);
            }

        __syncthreads();
    }

#pragma unroll
    for (int mi = 0; mi < 4; ++mi) {
#pragma unroll
        for (int ni = 0; ni < 2; ++ni) {
            const int rbase = tile_m * 128 + wm * 64 + mi * 16 + quad * 4;
            const int cg    = tile_n * 64 + wn * 32 + ni * 16 + r16;
            const float bv  = bias[cg];
#pragma unroll
            for (int r = 0; r < 4; ++r)
                C[(size_t)(rbase + r) * GN + cg] = acc[mi][ni][r] + bv;
        }
    }
}

extern "C" void kernel_launch(void* const* d_in, const int* in_sizes, int n_in,
                              void* d_out, int out_size, void* d_ws, size_t ws_size,
                              hipStream_t stream) {
    (void)in_sizes; (void)n_in; (void)out_size; (void)ws_size;
    const float* q    = (const float*)d_in[0];
    const float* k    = (const float*)d_in[1];
    const float* v    = (const float*)d_in[2];
    const float* W    = (const float*)d_in[3];
    const float* bias = (const float*)d_in[4];
    float*  out = (float*)d_out;
    ushort* y   = (ushort*)d_ws;   // 8 MiB bf16 scratch

    dim3 g1(T_SZ / QT, NH, B_SZ);          // (32, 16, 2) = 1024 blocks
    attn_mfma_kernel<<<g1, 256, 0, stream>>>(q, k, v, W, y);

    dim3 g2(GN / 64, GM / 128);            // (16, 32) = 512 blocks
    proj_gemm_kernel<<<g2, 256, 0, stream>>>(y, bias, out);
}